// Round 1
// baseline (2255.159 us; speedup 1.0000x reference)
//
#include <hip/hip_runtime.h>
#include <hip/hip_bf16.h>
#include <math.h>

// Problem constants (derived at runtime from in_sizes where possible)
#define F_IN   64
#define HC1    128   // H1*C1 = 4*32
#define C2v    64    // conv2 output channels (H2=1)

// ---------------------------------------------------------------------------
// CSR build: histogram -> scan (3 kernels) -> scatter
// ---------------------------------------------------------------------------
__global__ __launch_bounds__(256) void hist_kernel(const int* __restrict__ dst,
                                                   int* __restrict__ deg, int E) {
    int i = blockIdx.x * 256 + threadIdx.x;
    if (i < E) atomicAdd(&deg[dst[i]], 1);
}

__global__ __launch_bounds__(256) void scan_pass1(const int* __restrict__ deg,
                                                  int* __restrict__ bsum, int N) {
    __shared__ int sm[256];
    int t = threadIdx.x;
    int gid = blockIdx.x * 256 + t;
    sm[t] = (gid < N) ? deg[gid] : 0;
    __syncthreads();
    for (int off = 128; off > 0; off >>= 1) {
        if (t < off) sm[t] += sm[t + off];
        __syncthreads();
    }
    if (t == 0) bsum[blockIdx.x] = sm[0];
}

__global__ __launch_bounds__(256) void scan_pass2(int* __restrict__ bsum, int NB) {
    __shared__ int sm[256];
    int t = threadIdx.x;
    int v = (t < NB) ? bsum[t] : 0;
    sm[t] = v;
    __syncthreads();
    for (int off = 1; off < 256; off <<= 1) {
        int add = (t >= off) ? sm[t - off] : 0;
        __syncthreads();
        sm[t] += add;
        __syncthreads();
    }
    if (t < NB) bsum[t] = sm[t] - v;  // exclusive prefix of block sums
}

__global__ __launch_bounds__(256) void scan_pass3(const int* __restrict__ deg,
                                                  const int* __restrict__ bsum,
                                                  int* __restrict__ rowptr,
                                                  int* __restrict__ cursor,
                                                  int N, int E) {
    __shared__ int sm[256];
    int t = threadIdx.x;
    int gid = blockIdx.x * 256 + t;
    int v = (gid < N) ? deg[gid] : 0;
    sm[t] = v;
    __syncthreads();
    for (int off = 1; off < 256; off <<= 1) {
        int add = (t >= off) ? sm[t - off] : 0;
        __syncthreads();
        sm[t] += add;
        __syncthreads();
    }
    int ex = sm[t] - v + bsum[blockIdx.x];
    if (gid < N) { rowptr[gid] = ex; cursor[gid] = ex; }
    if (gid == 0) rowptr[N] = E;
}

__global__ __launch_bounds__(256) void scatter_kernel(const int* __restrict__ src,
                                                      const int* __restrict__ dst,
                                                      int* __restrict__ cursor,
                                                      int* __restrict__ csr, int E) {
    int i = blockIdx.x * 256 + threadIdx.x;
    if (i < E) {
        int p = atomicAdd(&cursor[dst[i]], 1);
        csr[p] = src[i];
    }
}

// ---------------------------------------------------------------------------
// GEMM: O[M,NOUT] = X[M,K] @ W[NOUT,K]^T + B   (fp32, LDS x-tile, W in regs)
// 256 threads, 32 rows per block.
// ---------------------------------------------------------------------------
template <int K, int NOUT>
__global__ __launch_bounds__(256) void gemm_bias(const float* __restrict__ X,
                                                 const float* __restrict__ W,
                                                 const float* __restrict__ B,
                                                 float* __restrict__ O, int M) {
    __shared__ float xs[32 * K];
    const int tid = threadIdx.x;
    const int rb = blockIdx.x * 32;

    // Stage 32 rows of X into LDS (coalesced float4)
    const int TOT4 = 32 * K / 4;
    const float4* X4 = (const float4*)(X + (size_t)rb * K);
    float4* xs4 = (float4*)xs;
    const int lim4 = (M - rb) * (K / 4);  // complete valid rows only
    for (int i = tid; i < TOT4; i += 256) {
        float4 v = make_float4(0.f, 0.f, 0.f, 0.f);
        if (i < lim4) v = X4[i];
        xs4[i] = v;
    }
    __syncthreads();

    constexpr int GROUPS = 256 / NOUT;
    constexpr int RPT = 32 / GROUPS;
    const int c = tid % NOUT;
    const int rg = tid / NOUT;

    float acc[RPT];
    const float bb = B[c];
#pragma unroll
    for (int r = 0; r < RPT; ++r) acc[r] = bb;

    const float4* W4 = (const float4*)W;
#pragma unroll
    for (int k0 = 0; k0 < K; k0 += 32) {
        float4 w[8];
#pragma unroll
        for (int j = 0; j < 8; ++j) w[j] = W4[c * (K / 4) + k0 / 4 + j];
#pragma unroll
        for (int r = 0; r < RPT; ++r) {
            const int row = rg * RPT + r;
            float a = 0.f;
#pragma unroll
            for (int j = 0; j < 8; ++j) {
                float4 xv = xs4[row * (K / 4) + k0 / 4 + j];
                a += w[j].x * xv.x + w[j].y * xv.y + w[j].z * xv.z + w[j].w * xv.w;
            }
            acc[r] += a;
        }
    }
#pragma unroll
    for (int r = 0; r < RPT; ++r) {
        const int row = rb + rg * RPT + r;
        if (row < M) O[(size_t)row * NOUT + c] = acc[r];
    }
}

// ---------------------------------------------------------------------------
// Fused GATv2 gather, layer 1: H=4 heads x C=32 channels (128 lanes = 128 ch)
// One block per dst node. Online softmax, single pass over incoming edges.
// Epilogue: /z, +bias, ELU.
// ---------------------------------------------------------------------------
__global__ __launch_bounds__(128) void gather1(const float* __restrict__ xl,
                                               const float* __restrict__ xr,
                                               const float* __restrict__ att,
                                               const float* __restrict__ bias,
                                               const int* __restrict__ rowptr,
                                               const int* __restrict__ csr,
                                               float* __restrict__ H) {
    const int dst = blockIdx.x;
    const int c = threadIdx.x;                  // channel = h*32 + cc
    const float xrc = xr[(size_t)dst * HC1 + c];
    const float ac = att[c];
    const int s0 = rowptr[dst];
    const int s1 = rowptr[dst + 1];

    float m = -INFINITY, z = 0.f, acc = 0.f;
    for (int i = s0; i < s1; ++i) {
        const int s = csr[i];
        const float xlc = xl[(size_t)s * HC1 + c];
        float t = xlc + xrc;
        t = (t > 0.f) ? t : 0.2f * t;          // LeakyReLU(0.2)
        float part = t * ac;
        // reduce across the 32-lane head group (masks <32 stay in-group)
#pragma unroll
        for (int off = 16; off >= 1; off >>= 1) part += __shfl_xor(part, off, 64);
        const float e = part;                   // identical across head group
        const float mn = fmaxf(m, e);
        const float scale = __expf(m - mn);     // m=-inf first iter -> 0
        const float p = __expf(e - mn);
        z = z * scale + p;
        acc = acc * scale + p * xlc;
        m = mn;
    }
    float o = acc / (z + 1e-16f) + bias[c];
    H[(size_t)dst * HC1 + c] = (o > 0.f) ? o : (__expf(o) - 1.f);  // ELU
}

// ---------------------------------------------------------------------------
// Fused GATv2 gather, layer 2: H=1 head x C=64 (one wave per dst node)
// ---------------------------------------------------------------------------
__global__ __launch_bounds__(64) void gather2(const float* __restrict__ xl,
                                              const float* __restrict__ xr,
                                              const float* __restrict__ att,
                                              const float* __restrict__ bias,
                                              const int* __restrict__ rowptr,
                                              const int* __restrict__ csr,
                                              float* __restrict__ O) {
    const int dst = blockIdx.x;
    const int c = threadIdx.x;
    const float xrc = xr[(size_t)dst * C2v + c];
    const float ac = att[c];
    const int s0 = rowptr[dst];
    const int s1 = rowptr[dst + 1];

    float m = -INFINITY, z = 0.f, acc = 0.f;
    for (int i = s0; i < s1; ++i) {
        const int s = csr[i];
        const float xlc = xl[(size_t)s * C2v + c];
        float t = xlc + xrc;
        t = (t > 0.f) ? t : 0.2f * t;
        float part = t * ac;
        // full 64-lane reduction (single head over all 64 channels)
#pragma unroll
        for (int off = 32; off >= 1; off >>= 1) part += __shfl_xor(part, off, 64);
        const float e = part;
        const float mn = fmaxf(m, e);
        const float scale = __expf(m - mn);
        const float p = __expf(e - mn);
        z = z * scale + p;
        acc = acc * scale + p * xlc;
        m = mn;
    }
    O[(size_t)dst * C2v + c] = acc / (z + 1e-16f) + bias[c];
}

// ---------------------------------------------------------------------------
extern "C" void kernel_launch(void* const* d_in, const int* in_sizes, int n_in,
                              void* d_out, int out_size, void* d_ws, size_t ws_size,
                              hipStream_t stream) {
    const float* x    = (const float*)d_in[0];
    const int* ei     = (const int*)d_in[1];
    const float* Wl1  = (const float*)d_in[2];
    const float* bl1  = (const float*)d_in[3];
    const float* Wr1  = (const float*)d_in[4];
    const float* br1  = (const float*)d_in[5];
    const float* att1 = (const float*)d_in[6];
    const float* bias1= (const float*)d_in[7];
    const float* Wl2  = (const float*)d_in[8];
    const float* bl2  = (const float*)d_in[9];
    const float* Wr2  = (const float*)d_in[10];
    const float* br2  = (const float*)d_in[11];
    const float* att2 = (const float*)d_in[12];
    const float* bias2= (const float*)d_in[13];
    float* out = (float*)d_out;

    const int N = in_sizes[0] / F_IN;      // 50000
    const int E = in_sizes[1] / 2;         // 850000
    const int* srcp = ei;
    const int* dstp = ei + E;

    // Workspace carve-up (256B aligned)
    char* ws = (char*)d_ws;
    size_t off = 0;
    auto carve = [&](size_t bytes) -> void* {
        void* p = ws + off;
        off = (off + bytes + 255) & ~(size_t)255;
        return p;
    };
    int* deg    = (int*)carve((size_t)N * 4);
    int* bsum   = (int*)carve(256 * 4);
    int* rowptr = (int*)carve((size_t)(N + 1) * 4);
    int* cursor = (int*)carve((size_t)N * 4);
    int* csr    = (int*)carve((size_t)E * 4);
    float* bufA = (float*)carve((size_t)N * HC1 * 4);  // xl1, later xl2
    float* bufB = (float*)carve((size_t)N * HC1 * 4);  // xr1, later xr2
    float* bufC = (float*)carve((size_t)N * HC1 * 4);  // h (elu output)
    (void)ws_size; (void)n_in; (void)out_size;

    const int EB = (E + 255) / 256;        // 3321
    const int NB = (N + 255) / 256;        // 196
    const int GB = (N + 31) / 32;          // 1563 gemm blocks

    // --- CSR build ---
    hipMemsetAsync(deg, 0, (size_t)N * 4, stream);
    hist_kernel<<<EB, 256, 0, stream>>>(dstp, deg, E);
    scan_pass1<<<NB, 256, 0, stream>>>(deg, bsum, N);
    scan_pass2<<<1, 256, 0, stream>>>(bsum, NB);
    scan_pass3<<<NB, 256, 0, stream>>>(deg, bsum, rowptr, cursor, N, E);
    scatter_kernel<<<EB, 256, 0, stream>>>(srcp, dstp, cursor, csr, E);

    // --- Layer 1 ---
    gemm_bias<F_IN, HC1><<<GB, 256, 0, stream>>>(x, Wl1, bl1, bufA, N);
    gemm_bias<F_IN, HC1><<<GB, 256, 0, stream>>>(x, Wr1, br1, bufB, N);
    gather1<<<N, 128, 0, stream>>>(bufA, bufB, att1, bias1, rowptr, csr, bufC);

    // --- Layer 2 ---
    gemm_bias<HC1, C2v><<<GB, 256, 0, stream>>>(bufC, Wl2, bl2, bufA, N);
    gemm_bias<HC1, C2v><<<GB, 256, 0, stream>>>(bufC, Wr2, br2, bufB, N);
    gather2<<<N, 64, 0, stream>>>(bufA, bufB, att2, bias2, rowptr, csr, out);
}